// Round 1
// baseline (175.516 us; speedup 1.0000x reference)
//
#include <hip/hip_runtime.h>

#define NITER 300

// readlane broadcast: uniform compile-time lane index -> v_readlane_b32 (SGPR, no LDS)
__device__ __forceinline__ float rdl(float v, int srclane) {
  return __int_as_float(__builtin_amdgcn_readlane(__float_as_int(v), srclane));
}

// ---------------------------------------------------------------------------
// Precompute: C = 10*Pddot'Pddot + 4.8*P'P + 10*Aeq'Aeq  (A_obs'A_obs = 4 P'P)
// Invert in f64 (Gauss-Jordan, SPD so diagonal pivots are safe), then store
//   ws[0..109]   = Q = -P  @ C^-1   (10x11)
//   ws[110..175] = R = -Aeq@ C^-1   (6x11)
// ---------------------------------------------------------------------------
__global__ void precomp_kernel(const float* __restrict__ P,
                               const float* __restrict__ Pdot,
                               const float* __restrict__ Pddot,
                               float* __restrict__ ws) {
  __shared__ double M[11][22];
  __shared__ double Aeq[6][11];
  __shared__ double Pd[10][11];
  const int t = threadIdx.x;

  if (t < 110) Pd[t / 11][t % 11] = (double)P[t];
  if (t < 66) {
    int e = t / 11, m = t % 11;
    const float* src = (e % 3 == 0) ? P : ((e % 3 == 1) ? Pdot : Pddot);
    int row = (e < 3) ? 0 : 9;
    Aeq[e][m] = (double)src[row * 11 + m];
  }
  __syncthreads();

  if (t < 121) {
    int a = t / 11, c2 = t % 11;
    double c = 0.0;
    for (int i = 0; i < 10; i++) c += 10.0 * (double)Pddot[i * 11 + a] * (double)Pddot[i * 11 + c2];
    for (int i = 0; i < 10; i++) c += 4.8 * Pd[i][a] * Pd[i][c2];
    for (int e = 0; e < 6; e++)  c += 10.0 * Aeq[e][a] * Aeq[e][c2];
    M[a][c2] = c;
    M[a][11 + c2] = (a == c2) ? 1.0 : 0.0;
  }
  __syncthreads();

  for (int p = 0; p < 11; p++) {
    if (t == p) {
      double inv = 1.0 / M[p][p];
      for (int c = 0; c < 22; c++) M[p][c] *= inv;
    }
    __syncthreads();
    if (t < 11 && t != p) {
      double f = M[t][p];
      for (int c = 0; c < 22; c++) M[t][c] -= f * M[p][c];
    }
    __syncthreads();
  }

  if (t < 110) {
    int i = t / 11, m = t % 11;
    double q = 0.0;
    for (int k = 0; k < 11; k++) q += Pd[i][k] * M[k][11 + m];
    ws[t] = (float)(-q);
  } else if (t < 176) {
    int e = (t - 110) / 11, m = (t - 110) % 11;
    double r = 0.0;
    for (int k = 0; k < 11; k++) r += Aeq[e][k] * M[k][11 + m];
    ws[t] = (float)(-r);
  }
}

// ---------------------------------------------------------------------------
// Main ADMM kernel: one wave (64 lanes) per batch element.
// Lane roles (coexisting register sets):
//   obs lanes  o=0..39  (o = 4*i + j; i=point 0..9, j=obstacle 0..3): wc/ws/u/res
//   NVAR lanes m=0..10: lin_x/lin_y, l_x/l_y (via pcolS = -1.2*P[:,m], aeqS = -10*Aeq[:,m])
//   req lanes 40..45: R rows, b_x/b_y elements
// All broadcasts via v_readlane; obstacle reduction via quad __shfl_xor(1,2).
// ---------------------------------------------------------------------------
__global__ __launch_bounds__(64) void admm_kernel(
    const float* __restrict__ x, const float* __restrict__ b,
    const float* __restrict__ W1, const float* __restrict__ b1,
    const float* __restrict__ W2, const float* __restrict__ b2,
    const float* __restrict__ P, const float* __restrict__ Pdot,
    const float* __restrict__ Pddot,
    const float* __restrict__ ws, float* __restrict__ out) {
  const int lane = threadIdx.x;
  const int bi = blockIdx.x;

  // ---- MLP: only b_pred[3] and b_pred[9] are needed (MASK zeros) ----
  float a1 = b1[lane];
  {
    const float* xr = x + bi * 16;
    const float* w1r = W1 + lane * 16;
    #pragma unroll
    for (int k = 0; k < 16; k++) a1 = fmaf(xr[k], w1r[k], a1);
  }
  float h = fmaxf(a1, 0.0f);
  float v3 = h * W2[3 * 64 + lane];
  float v9 = h * W2[9 * 64 + lane];
  #pragma unroll
  for (int dd = 32; dd >= 1; dd >>= 1) { v3 += __shfl_xor(v3, dd); v9 += __shfl_xor(v9, dd); }
  const float bp3 = v3 + b2[3];
  const float bp9 = v9 + b2[9];

  // ---- per-lane constant rows ----
  float m2A[11];  // lanes<40: Q[i]; 40..45: R[e]; else 0
  if (lane < 40) {
    const float* Qr = ws + (lane >> 2) * 11;
    #pragma unroll
    for (int k = 0; k < 11; k++) m2A[k] = Qr[k];
  } else if (lane < 46) {
    const float* Rr = ws + 110 + (lane - 40) * 11;
    #pragma unroll
    for (int k = 0; k < 11; k++) m2A[k] = Rr[k];
  } else {
    #pragma unroll
    for (int k = 0; k < 11; k++) m2A[k] = 0.0f;
  }

  const int m = (lane < 11) ? lane : 0;
  float pcolS[10];  // -1.2 * P[:, m]
  #pragma unroll
  for (int i = 0; i < 10; i++) pcolS[i] = -1.2f * P[i * 11 + m];
  float aeqS[6];    // -10 * Aeq[:, m]
  aeqS[0] = -10.0f * P[m];      aeqS[1] = -10.0f * Pdot[m];      aeqS[2] = -10.0f * Pddot[m];
  aeqS[3] = -10.0f * P[99 + m]; aeqS[4] = -10.0f * Pdot[99 + m]; aeqS[5] = -10.0f * Pddot[99 + m];

  // b elements at lanes 40..45 (index 3 comes from the MLP)
  float bxv = 0.0f, byv = 0.0f;
  if (lane >= 40 && lane < 46) {
    int e = lane - 40;
    bxv = (e == 3) ? bp3 : b[bi * 12 + e];
    byv = (e == 3) ? bp9 : b[bi * 12 + 6 + e];
  }

  // base = -1.2*S*colsum(P) - 10*(b @ Aeq)   (S = sum of obstacle coords)
  float sumS = 0.0f;
  #pragma unroll
  for (int i = 0; i < 10; i++) sumS += pcolS[i];
  float base_x = 130.79f * sumS;   // Sx = -10+100.79+30+10
  float base_y = 69.2f * sumS;     // Sy = -10+100-30.8+10
  #pragma unroll
  for (int e = 0; e < 6; e++) {
    base_x = fmaf(rdl(bxv, 40 + e), aeqS[e], base_x);
    base_y = fmaf(rdl(byv, 40 + e), aeqS[e], base_y);
  }

  const int j = lane & 3;
  const float xvl = (j == 0) ? -10.0f : (j == 1) ? 100.79f : (j == 2) ? 30.0f : 10.0f;
  const float yvl = (j == 0) ? -10.0f : (j == 1) ? 100.0f  : (j == 2) ? -30.8f : 10.0f;

  // state: u (obs lanes), l (NVAR lanes). alpha=0,d=1 -> u=(1,0)
  float ux = 1.0f, uy = 0.0f;
  float lx = 0.0f, ly = 0.0f;
  float tx = 0.0f, ty = 0.0f;

  for (int it = 0; it < NITER; ++it) {
    // column sums of u over the 4 obstacles (quad reduction)
    float cux = ux + __shfl_xor(ux, 1); cux += __shfl_xor(cux, 2);
    float cuy = uy + __shfl_xor(uy, 1); cuy += __shfl_xor(cuy, 2);

    // lin = base - l - 1.2 * (cu @ P)
    float linx = base_x - lx;
    float liny = base_y - ly;
    #pragma unroll
    for (int i = 0; i < 10; i++) {
      linx = fmaf(rdl(cux, 4 * i), pcolS[i], linx);
      liny = fmaf(rdl(cuy, 4 * i), pcolS[i], liny);
    }

    // every lane: acc = (its row) . lin   (obs lanes -> t, req lanes -> R.lin)
    float accA = 0.0f, accB = 0.0f;
    #pragma unroll
    for (int k = 0; k < 11; k++) {
      accA = fmaf(rdl(linx, k), m2A[k], accA);
      accB = fmaf(rdl(liny, k), m2A[k], accB);
    }
    tx = accA; ty = accB;

    // obstacle projection (no trig: u = max(1, 1/r) * w)
    float wc = accA - xvl;
    float wsv = accB - yvl;
    float r2 = fmaf(wc, wc, wsv * wsv);
    float s = fmaxf(1.0f, __builtin_amdgcn_rsqf(r2));
    float nux = (r2 > 0.0f) ? s * wc  : 1.0f;   // atan2(0,0)=0 -> (ca,sa)=(1,0)
    float nuy = (r2 > 0.0f) ? s * wsv : 0.0f;
    float rsx = wc - nux, rsy = wsv - nuy;
    ux = nux; uy = nuy;

    // residual column sums + eq residuals
    float crx = rsx + __shfl_xor(rsx, 1); crx += __shfl_xor(crx, 2);
    float cry = rsy + __shfl_xor(rsy, 1); cry += __shfl_xor(cry, 2);
    float reqx = accA - bxv;   // valid on lanes 40..45
    float reqy = accB - byv;

    // l -= 1.2*(cr @ P) + 10*(req @ Aeq)   (signs folded into pcolS/aeqS)
    float dlx = 0.0f, dly = 0.0f;
    #pragma unroll
    for (int i = 0; i < 10; i++) {
      dlx = fmaf(rdl(crx, 4 * i), pcolS[i], dlx);
      dly = fmaf(rdl(cry, 4 * i), pcolS[i], dly);
    }
    #pragma unroll
    for (int e = 0; e < 6; e++) {
      dlx = fmaf(rdl(reqx, 40 + e), aeqS[e], dlx);
      dly = fmaf(rdl(reqy, 40 + e), aeqS[e], dly);
    }
    lx += dlx;
    ly += dly;
  }

  // output = t from the final iteration (== sol @ P.T)
  if (lane < 40 && (lane & 3) == 0) {
    const int i = lane >> 2;
    out[bi * 20 + i] = tx;
    out[bi * 20 + 10 + i] = ty;
  }
}

extern "C" void kernel_launch(void* const* d_in, const int* in_sizes, int n_in,
                              void* d_out, int out_size, void* d_ws, size_t ws_size,
                              hipStream_t stream) {
  const float* x     = (const float*)d_in[0];
  const float* b     = (const float*)d_in[1];
  const float* W1    = (const float*)d_in[2];
  const float* b1    = (const float*)d_in[3];
  const float* W2    = (const float*)d_in[4];
  const float* b2    = (const float*)d_in[5];
  const float* P     = (const float*)d_in[6];
  const float* Pdot  = (const float*)d_in[7];
  const float* Pddot = (const float*)d_in[8];
  float* ws  = (float*)d_ws;
  float* out = (float*)d_out;

  const int B = in_sizes[0] / 16;  // 512

  precomp_kernel<<<1, 256, 0, stream>>>(P, Pdot, Pddot, ws);
  admm_kernel<<<B, 64, 0, stream>>>(x, b, W1, b1, W2, b2, P, Pdot, Pddot, ws, out);
}

// Round 2
// 79.360 us; speedup vs baseline: 2.2116x; 2.2116x over previous
//
#include <hip/hip_runtime.h>

#define NBODY 299  // prologue computes t^(1); 299 body iters -> t^(300)

// readlane broadcast: uniform compile-time lane index -> v_readlane_b32 (SGPR)
__device__ __forceinline__ float rdl(float v, int srclane) {
  return __int_as_float(__builtin_amdgcn_readlane(__float_as_int(v), srclane));
}

// quad sum via DPP quad_perm (VALU pipe, no LDS): [1,0,3,2]=0xB1, [2,3,0,1]=0x4E
__device__ __forceinline__ float qsum4(float v) {
  v += __int_as_float(__builtin_amdgcn_update_dpp(0, __float_as_int(v), 0xB1, 0xF, 0xF, false));
  v += __int_as_float(__builtin_amdgcn_update_dpp(0, __float_as_int(v), 0x4E, 0xF, 0xF, false));
  return v;
}

// ---------------------------------------------------------------------------
// Precompute (f64): C = 10*Pddot'Pddot + 4.8*P'P + 10*Aeq'Aeq;  Cinv via GJ.
// Q = -P@Cinv (10x11), R = -Aeq@Cinv (6x11). Then per-row fused matrices:
//   Gt = 1.2*Q@P'   (10x10)   Ht = 10*Q@Aeq'   (10x6)
//   Gr = 1.2*R@P'   (6x10)    Hr = 10*R@Aeq'   (6x6)
// ws layout: blk=0..9 -> [Gt[blk][0..9], Ht[blk][0..5]] at ws[blk*16+..]
//            blk=10..15 (e=blk-10) -> [Gr[e][..], Hr[e][..]]
//            ws[256+blk] = rowsum(G) (Gt*1 or Gr*1)
// ---------------------------------------------------------------------------
__global__ void precomp_kernel(const float* __restrict__ P,
                               const float* __restrict__ Pdot,
                               const float* __restrict__ Pddot,
                               float* __restrict__ ws) {
  __shared__ double M[11][22];
  __shared__ double Aq[6][11];
  __shared__ double Pd[10][11];
  __shared__ double QR[16][11];
  const int t = threadIdx.x;

  if (t < 110) Pd[t / 11][t % 11] = (double)P[t];
  if (t < 66) {
    int e = t / 11, m = t % 11;
    const float* src = (e % 3 == 0) ? P : ((e % 3 == 1) ? Pdot : Pddot);
    int row = (e < 3) ? 0 : 9;
    Aq[e][m] = (double)src[row * 11 + m];
  }
  __syncthreads();

  if (t < 121) {
    int a = t / 11, c2 = t % 11;
    double c = 0.0;
    for (int i = 0; i < 10; i++) c += 10.0 * (double)Pddot[i * 11 + a] * (double)Pddot[i * 11 + c2];
    for (int i = 0; i < 10; i++) c += 4.8 * Pd[i][a] * Pd[i][c2];
    for (int e = 0; e < 6; e++)  c += 10.0 * Aq[e][a] * Aq[e][c2];
    M[a][c2] = c;
    M[a][11 + c2] = (a == c2) ? 1.0 : 0.0;
  }
  __syncthreads();

  for (int p = 0; p < 11; p++) {
    if (t == p) {
      double inv = 1.0 / M[p][p];
      for (int c = 0; c < 22; c++) M[p][c] *= inv;
    }
    __syncthreads();
    if (t < 11 && t != p) {
      double f = M[t][p];
      for (int c = 0; c < 22; c++) M[t][c] -= f * M[p][c];
    }
    __syncthreads();
  }

  if (t < 176) {
    int blk = t / 11, m = t % 11;
    double q = 0.0;
    if (blk < 10) { for (int k = 0; k < 11; k++) q += Pd[blk][k] * M[k][11 + m]; }
    else          { for (int k = 0; k < 11; k++) q += Aq[blk - 10][k] * M[k][11 + m]; }
    QR[blk][m] = -q;
  }
  __syncthreads();

  {
    int blk = t >> 4, c = t & 15;
    double v = 0.0;
    if (c < 10) {
      for (int m = 0; m < 11; m++) v += QR[blk][m] * Pd[c][m];
      v *= 1.2;
    } else {
      int e = c - 10;
      for (int m = 0; m < 11; m++) v += QR[blk][m] * Aq[e][m];
      v *= 10.0;
    }
    ws[t] = (float)v;
  }
  if (t < 16) {
    double v = 0.0;
    for (int m = 0; m < 11; m++) {
      double cs = 0.0;
      for (int k = 0; k < 10; k++) cs += Pd[k][m];
      v += QR[t][m] * cs;
    }
    ws[256 + t] = (float)(1.2 * v);
  }
}

// ---------------------------------------------------------------------------
// ADMM, restructured state space. One wave per batch element.
// Lanes 0..39 (o=4i+j): trajectory row i; lanes 40..45: eq-residual row e.
// State per lane: s (x,y), t (x,y). Recurrence (per coord):
//   proj: w = t - obs; u = max(1,1/|w|)*w ; cu = quadsum(u)
//   A = s - gtc + sum_k G[k]*(4*t_k) + sum_e H[e]*req_e   (broadcasts via rdl)
//   n = sum_k G[k]*cu_k
//   s' = A - n ; t' = s' - n
// where gtc = SumObs * rowsum(G). req lanes run the identical code with G=Gr,H=Hr.
// ---------------------------------------------------------------------------
__global__ __launch_bounds__(64) void admm_kernel(
    const float* __restrict__ x, const float* __restrict__ b,
    const float* __restrict__ W1, const float* __restrict__ b1,
    const float* __restrict__ W2, const float* __restrict__ b2,
    const float* __restrict__ ws, float* __restrict__ out) {
  const int lane = threadIdx.x;
  const int bi = blockIdx.x;

  // ---- MLP: only b_pred[3] and b_pred[9] survive the mask ----
  float a1 = b1[lane];
  {
    const float* xr = x + bi * 16;
    const float* w1r = W1 + lane * 16;
    #pragma unroll
    for (int k = 0; k < 16; k++) a1 = fmaf(xr[k], w1r[k], a1);
  }
  float hh = fmaxf(a1, 0.0f);
  float v3 = hh * W2[3 * 64 + lane];
  float v9 = hh * W2[9 * 64 + lane];
  #pragma unroll
  for (int dd = 32; dd >= 1; dd >>= 1) { v3 += __shfl_xor(v3, dd); v9 += __shfl_xor(v9, dd); }
  const float bp3 = v3 + b2[3];
  const float bp9 = v9 + b2[9];

  // ---- per-lane constant rows ----
  const int blk = (lane < 40) ? (lane >> 2) : ((lane < 46) ? (10 + lane - 40) : -1);
  float g[10], h[6], G1 = 0.0f;
  if (blk >= 0) {
    const float* r = ws + blk * 16;
    #pragma unroll
    for (int k = 0; k < 10; k++) g[k] = r[k];
    #pragma unroll
    for (int e = 0; e < 6; e++) h[e] = r[10 + e];
    G1 = ws[256 + blk];
  } else {
    #pragma unroll
    for (int k = 0; k < 10; k++) g[k] = 0.0f;
    #pragma unroll
    for (int e = 0; e < 6; e++) h[e] = 0.0f;
  }

  // b elements on req lanes (index 3 from MLP)
  float bown = 0.0f, bowny = 0.0f;
  if (lane >= 40 && lane < 46) {
    int e = lane - 40;
    bown  = (e == 3) ? bp3 : b[bi * 12 + e];
    bowny = (e == 3) ? bp9 : b[bi * 12 + 6 + e];
  }

  const float gtcx = 130.79f * G1;  // SumX_obs = -10+100.79+30+10
  const float gtcy = 69.2f  * G1;   // SumY_obs = -10+100-30.8+10

  // s0 = -gtc - H*b  (req lanes additionally -b_own)
  float sx = -gtcx, sy = -gtcy;
  #pragma unroll
  for (int e = 0; e < 6; e++) {
    sx = fmaf(-h[e], rdl(bown,  40 + e), sx);
    sy = fmaf(-h[e], rdl(bowny, 40 + e), sy);
  }
  if (lane >= 40 && lane < 46) { sx -= bown; sy -= bowny; }

  // t^(1): cu0 = (4,...,4) for x, 0 for y  ->  n0x = 4*rowsum(G)
  float tx = fmaf(-4.0f, G1, sx);
  float ty = sy;

  const int j = lane & 3;
  const float xvl = (j == 0) ? -10.0f : (j == 1) ? 100.79f : (j == 2) ? 30.0f : 10.0f;
  const float yvl = (j == 0) ? -10.0f : (j == 1) ? 100.0f  : (j == 2) ? -30.8f : 10.0f;

  for (int it = 0; it < NBODY; ++it) {
    // projection (both coords couple only here)
    float wx = tx - xvl;
    float wy = ty - yvl;
    float r2 = fmaf(wx, wx, wy * wy);
    float sc = fmaxf(1.0f, __builtin_amdgcn_rsqf(r2));
    float ux = (r2 > 0.0f) ? sc * wx : 1.0f;
    float uy = (r2 > 0.0f) ? sc * wy : 0.0f;
    float cux = qsum4(ux);
    float cuy = qsum4(uy);

    float t4x = 4.0f * tx;
    float t4y = 4.0f * ty;

    // A = s - gtc + G.(4t) + H.req   (16-deep fma chains, x/y interleaved)
    float Ax = sx - gtcx;
    float Ay = sy - gtcy;
    #pragma unroll
    for (int k = 0; k < 10; k++) {
      Ax = fmaf(g[k], rdl(t4x, 4 * k), Ax);
      Ay = fmaf(g[k], rdl(t4y, 4 * k), Ay);
    }
    #pragma unroll
    for (int e = 0; e < 6; e++) {
      Ax = fmaf(h[e], rdl(tx, 40 + e), Ax);
      Ay = fmaf(h[e], rdl(ty, 40 + e), Ay);
    }

    // n = G.cu  (independent 10-deep chains)
    float nx = 0.0f, ny = 0.0f;
    #pragma unroll
    for (int k = 0; k < 10; k++) {
      nx = fmaf(g[k], rdl(cux, 4 * k), nx);
      ny = fmaf(g[k], rdl(cuy, 4 * k), ny);
    }

    sx = Ax - nx; tx = sx - nx;
    sy = Ay - ny; ty = sy - ny;
  }

  if (lane < 40 && (lane & 3) == 0) {
    const int i = lane >> 2;
    out[bi * 20 + i] = tx;
    out[bi * 20 + 10 + i] = ty;
  }
}

extern "C" void kernel_launch(void* const* d_in, const int* in_sizes, int n_in,
                              void* d_out, int out_size, void* d_ws, size_t ws_size,
                              hipStream_t stream) {
  const float* x     = (const float*)d_in[0];
  const float* b     = (const float*)d_in[1];
  const float* W1    = (const float*)d_in[2];
  const float* b1    = (const float*)d_in[3];
  const float* W2    = (const float*)d_in[4];
  const float* b2    = (const float*)d_in[5];
  const float* P     = (const float*)d_in[6];
  const float* Pdot  = (const float*)d_in[7];
  const float* Pddot = (const float*)d_in[8];
  float* ws  = (float*)d_ws;
  float* out = (float*)d_out;

  const int B = in_sizes[0] / 16;  // 512

  precomp_kernel<<<1, 256, 0, stream>>>(P, Pdot, Pddot, ws);
  admm_kernel<<<B, 64, 0, stream>>>(x, b, W1, b1, W2, b2, ws, out);
}